// Round 4
// baseline (4696.721 us; speedup 1.0000x reference)
//
#include <hip/hip_runtime.h>
#include <hip/hip_bf16.h>
#include <math.h>

constexpr int B = 64, N = 307, F = 64, T = 12, K = 3, C = 64, CT = 64;
constexpr float LN_EPS = 1e-5f;

// ---------------- temporal attention ----------------

// lhs1_e[b,t,f] = sum_n x[b,n,f,t] * U1[n]
__global__ void k_lhs1_e(const float* __restrict__ x, const float* __restrict__ U1,
                         float* __restrict__ out) {
    int idx = blockIdx.x * blockDim.x + threadIdx.x;
    if (idx >= B * T * F) return;
    int f = idx % F;
    int t = (idx / F) % T;
    int b = idx / (F * T);
    const float* xp = x + ((size_t)b * N * F + f) * T + t;
    float s = 0.f;
    for (int n = 0; n < N; n++) s += xp[(size_t)n * F * T] * U1[n];
    out[idx] = s;
}

// rhs_e[b,n,t] = sum_f U3[f] * x[b,n,f,t]
__global__ void k_rhs_e(const float* __restrict__ x, const float* __restrict__ U3,
                        float* __restrict__ out) {
    int idx = blockIdx.x * blockDim.x + threadIdx.x;
    if (idx >= B * N * T) return;
    int t = idx % T;
    size_t bn = idx / T;
    const float* xp = x + bn * F * T + t;
    float s = 0.f;
    for (int f = 0; f < F; f++) s += U3[f] * xp[f * T];
    out[idx] = s;
}

// lhs_e[b,t,n] = sum_f lhs1_e[b,t,f] * U2[f,n]
__global__ void k_lhs_e(const float* __restrict__ lhs1, const float* __restrict__ U2,
                        float* __restrict__ out) {
    int idx = blockIdx.x * blockDim.x + threadIdx.x;
    if (idx >= B * T * N) return;
    int n = idx % N;
    int bt = idx / N;
    const float* lp = lhs1 + (size_t)bt * F;
    float s = 0.f;
    for (int f = 0; f < F; f++) s += lp[f] * U2[f * N + n];
    out[idx] = s;
}

// prod/sigmoid/V_e/softmax fused per batch: E[b,u,t] softmaxed over u
__global__ void k_tatt(const float* __restrict__ lhs, const float* __restrict__ rhs,
                       const float* __restrict__ b_e, const float* __restrict__ V_e,
                       float* __restrict__ E) {
    int b = blockIdx.x;
    int tid = threadIdx.x;
    __shared__ float sig[T * T];
    __shared__ float Ev[T * T];
    __shared__ float mx[T], sm[T];
    if (tid < T * T) {
        int t = tid % T, u = tid / T;
        const float* lp = lhs + ((size_t)b * T + u) * N;
        const float* rp = rhs + (size_t)b * N * T + t;
        float s = 0.f;
        for (int n = 0; n < N; n++) s += lp[n] * rp[(size_t)n * T];
        s += b_e[u * T + t];
        sig[tid] = 1.f / (1.f + expf(-s));
    }
    __syncthreads();
    if (tid < T * T) {
        int t = tid % T, u = tid / T;
        float e = 0.f;
        for (int v = 0; v < T; v++) e += V_e[u * T + v] * sig[v * T + t];
        Ev[tid] = e;
    }
    __syncthreads();
    if (tid < T) {
        float m = -1e30f;
        for (int u = 0; u < T; u++) m = fmaxf(m, Ev[u * T + tid]);
        float s = 0.f;
        for (int u = 0; u < T; u++) s += expf(Ev[u * T + tid] - m);
        mx[tid] = m;
        sm[tid] = s;
    }
    __syncthreads();
    if (tid < T * T) {
        int t = tid % T;
        E[(size_t)b * T * T + tid] = expf(Ev[tid] - mx[t]) / sm[t];
    }
}

// EW1[b,tp] = sum_t E[b,tp,t] * W1[t]
__global__ void k_EW1(const float* __restrict__ E, const float* __restrict__ W1,
                      float* __restrict__ out) {
    int idx = blockIdx.x * blockDim.x + threadIdx.x;
    if (idx >= B * T) return;
    const float* Ep = E + (size_t)idx * T;
    float s = 0.f;
    for (int t = 0; t < T; t++) s += Ep[t] * W1[t];
    out[idx] = s;
}

// ---------------- spatial attention (x_TAt folded in algebraically) ----------------

// lhs_s[b,n,t] = sum_f (sum_tp x[b,n,f,tp]*EW1[b,tp]) * W2[f,t]
__global__ void k_lhs_sf(const float* __restrict__ x, const float* __restrict__ EW1,
                         const float* __restrict__ W2, float* __restrict__ lhs_s) {
    int bn = blockIdx.x;
    int b = bn / N;
    int tid = threadIdx.x;  // 64
    __shared__ float a[F];
    __shared__ float ew[T];
    if (tid < T) ew[tid] = EW1[(size_t)b * T + tid];
    __syncthreads();
    const float* xp = x + (size_t)bn * F * T + tid * T;  // row f = tid
    float s = 0.f;
    for (int tp = 0; tp < T; tp++) s += xp[tp] * ew[tp];
    a[tid] = s;
    __syncthreads();
    if (tid < T) {
        float s2 = 0.f;
        for (int f = 0; f < F; f++) s2 += a[f] * W2[f * T + tid];
        lhs_s[(size_t)bn * T + tid] = s2;
    }
}

// xw3[b,m,tp] = sum_f W3[f] * x[b,m,f,tp]
__global__ void k_xw3(const float* __restrict__ x, const float* __restrict__ W3,
                      float* __restrict__ out) {
    int idx = blockIdx.x * blockDim.x + threadIdx.x;
    if (idx >= B * N * T) return;
    int tp = idx % T;
    size_t bm = idx / T;
    const float* xp = x + bm * F * T + tp;
    float s = 0.f;
    for (int f = 0; f < F; f++) s += W3[f] * xp[f * T];
    out[idx] = s;
}

// rhs_s[b,t,m] = sum_tp xw3[b,m,tp] * E[b,tp,t]
__global__ void k_rhs_s2(const float* __restrict__ xw3, const float* __restrict__ E,
                         float* __restrict__ out) {
    int idx = blockIdx.x * blockDim.x + threadIdx.x;
    if (idx >= B * T * N) return;
    int m = idx % N;
    int t = (idx / N) % T;
    int b = idx / (N * T);
    const float* xp = xw3 + ((size_t)b * N + m) * T;
    const float* Ep = E + (size_t)b * T * T + t;
    float s = 0.f;
    for (int tp = 0; tp < T; tp++) s += xp[tp] * Ep[tp * T];
    out[idx] = s;
}

// VsT[v,i] = V_s[i,v]
__global__ void k_transposeVs(const float* __restrict__ V, float* __restrict__ VT) {
    int idx = blockIdx.x * blockDim.x + threadIdx.x;
    if (idx >= N * N) return;
    int v = idx % N;
    int i = idx / N;
    VT[(size_t)v * N + i] = V[(size_t)i * N + v];
}

// fused: sig row -> S row.  block per (b,a), 256 threads.
// sig[v] = sigmoid( sum_t lhs_s[b,a,t]*rhs_s[b,t,v] + b_s[a,v] )
// S[b,a,i] = sum_v sig[v] * V_s[i,v]  (= sig . VsT[:,i])
__global__ void k_sigS(const float* __restrict__ lhs_s, const float* __restrict__ rhs_s,
                       const float* __restrict__ b_s, const float* __restrict__ VsT,
                       float* __restrict__ S) {
    int blk = blockIdx.x;  // b*N + a
    int b = blk / N;
    int a = blk % N;
    int tid = threadIdx.x;  // 256
    __shared__ float lrow[T];
    __shared__ float sigrow[N];
    if (tid < T) lrow[tid] = lhs_s[(size_t)blk * T + tid];
    __syncthreads();
    for (int v = tid; v < N; v += 256) {
        float s = 0.f;
        for (int t = 0; t < T; t++) s += lrow[t] * rhs_s[((size_t)b * T + t) * N + v];
        s += b_s[(size_t)a * N + v];
        sigrow[v] = 1.f / (1.f + expf(-s));
    }
    __syncthreads();
    for (int i = tid; i < N; i += 256) {
        float s = 0.f;
        for (int v = 0; v < N; v++) s += sigrow[v] * VsT[(size_t)v * N + i];
        S[(size_t)blk * N + i] = s;
    }
}

// softmax over a (axis 1) for each (b, i)
__global__ void k_softmax_S(float* __restrict__ S) {
    int idx = blockIdx.x * blockDim.x + threadIdx.x;
    if (idx >= B * N) return;
    int b = idx / N;
    int i = idx % N;
    float* p = S + (size_t)b * N * N + i;
    float m = -1e30f;
    for (int a = 0; a < N; a++) m = fmaxf(m, p[(size_t)a * N]);
    float s = 0.f;
    for (int a = 0; a < N; a++) s += expf(p[(size_t)a * N] - m);
    float inv = 1.f / s;
    for (int a = 0; a < N; a++) p[(size_t)a * N] = expf(p[(size_t)a * N] - m) * inv;
}

// ---------------- fused cheb graph conv + theta + relu + tconv + rconv + LN ----------------
// z_k[b,j,f,t] = sum_i (cheb[k,i,j]*S[b,i,j]) * x[b,i,f,t]
// sg[b,j,c,t]  = relu( sum_k sum_f z_k * Theta[k,f,c] )
// h[b,j,ct,t]  = relu( rconv(x) + tconv(sg) );  out = LN_ct(h)*gamma+beta

constexpr int JT = 4;
constexpr int NJB = (N + JT - 1) / JT;  // 77
constexpr int FT = F * T;               // 768

__global__ void __launch_bounds__(256, 1)
k_gcnz_final(const float* __restrict__ x, const float* __restrict__ S,
             const float* __restrict__ cheb, const float* __restrict__ Theta,
             const float* __restrict__ tw, const float* __restrict__ tb,
             const float* __restrict__ rw, const float* __restrict__ rb,
             const float* __restrict__ gamma, const float* __restrict__ beta,
             float* __restrict__ out) {
    int blk = blockIdx.x;
    int b = blk / NJB;
    int j0 = (blk % NJB) * JT;
    int tid = threadIdx.x;  // 256

    __shared__ float wl[K][64][JT];   // 12 KB
    __shared__ float zl[K][JT][FT];   // 36 KB (reused as hl later)
    __shared__ float sg[JT][FT];      // 12 KB
    __shared__ float xl[JT][FT];      // 12 KB
    __shared__ float mu[JT][T], rstd[JT][T];

    float acc[K][JT][3];
    for (int k = 0; k < K; k++)
        for (int jj = 0; jj < JT; jj++)
            for (int r = 0; r < 3; r++) acc[k][jj][r] = 0.f;

    const float* xb = x + (size_t)b * N * FT;

    for (int ic = 0; ic < N; ic += 64) {
        for (int l = tid; l < K * 64 * JT; l += 256) {
            int k = l / (64 * JT);
            int rem = l % (64 * JT);
            int ii = rem / JT, jj = rem % JT;
            int i = ic + ii, j = j0 + jj;
            float w = 0.f;
            if (i < N && j < N)
                w = cheb[((size_t)k * N + i) * N + j] * S[((size_t)b * N + i) * N + j];
            wl[k][ii][jj] = w;
        }
        __syncthreads();
        int imax = min(64, N - ic);
        for (int ii = 0; ii < imax; ii++) {
            const float* xr = xb + (size_t)(ic + ii) * FT;
            float xv[3];
            for (int r = 0; r < 3; r++) xv[r] = xr[tid + 256 * r];
            for (int k = 0; k < K; k++)
                for (int jj = 0; jj < JT; jj++) {
                    float w = wl[k][ii][jj];
                    for (int r = 0; r < 3; r++) acc[k][jj][r] += w * xv[r];
                }
        }
        __syncthreads();
    }

    // z -> LDS; also stage x rows for rconv
    for (int k = 0; k < K; k++)
        for (int jj = 0; jj < JT; jj++)
            for (int r = 0; r < 3; r++) zl[k][jj][tid + 256 * r] = acc[k][jj][r];
    for (int jj = 0; jj < JT; jj++) {
        int j = j0 + jj;
        for (int r = 0; r < 3; r++)
            xl[jj][tid + 256 * r] = (j < N) ? xb[(size_t)j * FT + tid + 256 * r] : 0.f;
    }
    __syncthreads();

    // Theta contraction + relu -> sg  (j>=N lanes produce zeros; harmless)
    for (int jj = 0; jj < JT; jj++) {
        for (int r = 0; r < 3; r++) {
            int e = tid + 256 * r;  // c*T + t
            int c = e / T;
            int t = e % T;
            float s = 0.f;
            for (int k = 0; k < K; k++) {
                const float* zp = &zl[k][jj][t];
                const float* tp = Theta + (size_t)k * F * C + c;
                for (int f = 0; f < F; f++) s += zp[f * T] * tp[f * C];
            }
            sg[jj][e] = fmaxf(s, 0.f);
        }
    }
    __syncthreads();

    // h = relu(rconv + tconv) -> reuse zl region as hl[JT][FT]
    float* hl = &zl[0][0][0];
    for (int jj = 0; jj < JT; jj++) {
        for (int r = 0; r < 3; r++) {
            int e = tid + 256 * r;  // ct*T + t
            int ct = e / T;
            int t = e % T;
            float res = rb[ct];
            const float* rwp = rw + (size_t)ct * F;
            for (int f = 0; f < F; f++) res += xl[jj][f * T + t] * rwp[f];
            float tco = tb[ct];
            const float* twp = tw + (size_t)ct * C * 3;
            const float* sgj = sg[jj];
            for (int c = 0; c < C; c++) {
                float s0 = (t > 0) ? sgj[c * T + t - 1] : 0.f;
                float s1 = sgj[c * T + t];
                float s2 = (t < T - 1) ? sgj[c * T + t + 1] : 0.f;
                tco += s0 * twp[c * 3 + 0] + s1 * twp[c * 3 + 1] + s2 * twp[c * 3 + 2];
            }
            hl[jj * FT + e] = fmaxf(res + tco, 0.f);
        }
    }
    __syncthreads();

    // LN stats per (jj, t)
    if (tid < JT * T) {
        int jj = tid / T;
        int t = tid % T;
        float m = 0.f;
        for (int ct = 0; ct < CT; ct++) m += hl[jj * FT + ct * T + t];
        m /= CT;
        float v = 0.f;
        for (int ct = 0; ct < CT; ct++) {
            float d = hl[jj * FT + ct * T + t] - m;
            v += d * d;
        }
        v /= CT;
        mu[jj][t] = m;
        rstd[jj][t] = rsqrtf(v + LN_EPS);
    }
    __syncthreads();

    // normalize + affine + coalesced store: out[bn*FT + e], e = ct*T + t
    for (int jj = 0; jj < JT; jj++) {
        int j = j0 + jj;
        if (j >= N) continue;
        float* op = out + ((size_t)b * N + j) * FT;
        for (int r = 0; r < 3; r++) {
            int e = tid + 256 * r;
            int ct = e / T;
            int t = e % T;
            op[e] = (hl[jj * FT + e] - mu[jj][t]) * rstd[jj][t] * gamma[ct] + beta[ct];
        }
    }
}

// ---------------- launch ----------------

extern "C" void kernel_launch(void* const* d_in, const int* in_sizes, int n_in,
                              void* d_out, int out_size, void* d_ws, size_t ws_size,
                              hipStream_t stream) {
    const float* x     = (const float*)d_in[0];
    const float* W1    = (const float*)d_in[1];
    const float* W2    = (const float*)d_in[2];
    const float* W3    = (const float*)d_in[3];
    const float* b_s   = (const float*)d_in[4];
    const float* V_s   = (const float*)d_in[5];
    const float* U1    = (const float*)d_in[6];
    const float* U2    = (const float*)d_in[7];
    const float* U3    = (const float*)d_in[8];
    const float* b_e   = (const float*)d_in[9];
    const float* V_e   = (const float*)d_in[10];
    const float* cheb  = (const float*)d_in[11];
    const float* Theta = (const float*)d_in[12];
    const float* tw    = (const float*)d_in[13];
    const float* tb    = (const float*)d_in[14];
    const float* rw    = (const float*)d_in[15];
    const float* rb    = (const float*)d_in[16];
    const float* gam   = (const float*)d_in[17];
    const float* bet   = (const float*)d_in[18];
    float* out = (float*)d_out;

    // workspace (floats): total ~7.36 M floats = ~29.5 MB
    float* ws = (float*)d_ws;
    size_t off = 0;
    auto alloc = [&](size_t n) { float* p = ws + off; off += n; return p; };
    float* Sb     = alloc((size_t)B * N * N);   // 6,031,936
    float* VsT    = alloc((size_t)N * N);
    float* lhs1_e = alloc((size_t)B * T * F);
    float* lhs_e  = alloc((size_t)B * T * N);
    float* rhs_e  = alloc((size_t)B * N * T);
    float* Ebuf   = alloc((size_t)B * T * T);
    float* EW1    = alloc((size_t)B * T);
    float* xw3    = alloc((size_t)B * N * T);
    float* lhs_s  = alloc((size_t)B * N * T);
    float* rhs_s  = alloc((size_t)B * T * N);

    auto g = [](long n) { return dim3((unsigned)((n + 255) / 256)); };

    // temporal attention
    k_lhs1_e<<<g((long)B * T * F), 256, 0, stream>>>(x, U1, lhs1_e);
    k_rhs_e<<<g((long)B * N * T), 256, 0, stream>>>(x, U3, rhs_e);
    k_lhs_e<<<g((long)B * T * N), 256, 0, stream>>>(lhs1_e, U2, lhs_e);
    k_tatt<<<B, 256, 0, stream>>>(lhs_e, rhs_e, b_e, V_e, Ebuf);

    // spatial attention (x_TAt folded in)
    k_EW1<<<g((long)B * T), 256, 0, stream>>>(Ebuf, W1, EW1);
    k_lhs_sf<<<B * N, 64, 0, stream>>>(x, EW1, W2, lhs_s);
    k_xw3<<<g((long)B * N * T), 256, 0, stream>>>(x, W3, xw3);
    k_rhs_s2<<<g((long)B * T * N), 256, 0, stream>>>(xw3, Ebuf, rhs_s);
    k_transposeVs<<<g((long)N * N), 256, 0, stream>>>(V_s, VsT);
    k_sigS<<<B * N, 256, 0, stream>>>(lhs_s, rhs_s, b_s, VsT, Sb);
    k_softmax_S<<<g((long)B * N), 256, 0, stream>>>(Sb);

    // fused graph conv + theta + tconv + rconv + LN -> writes d_out directly
    k_gcnz_final<<<B * NJB, 256, 0, stream>>>(x, Sb, cheb, Theta,
                                              tw, tb, rw, rb, gam, bet, out);
}